// Round 2
// baseline (513.966 us; speedup 1.0000x reference)
//
#include <hip/hip_runtime.h>

// MultiHeadGraphAttention: n=4096, n_head=8, f_in=1024, f_out=128
// score = s_i + d_j (rank-1); exp(leakyrelu(x)) separable:
//   x>=0: e^s * e^d  (test e^s*e^d >= 1),  x<0: e^{.2s} * e^{.2d}
// Dtype-adaptive: detects whether float inputs are bf16 or fp32 at runtime.

#define N 4096
#define NH 8
#define FIN 1024
#define FOUT 128

typedef short bf16x8 __attribute__((ext_vector_type(8)));
typedef float f32x4 __attribute__((ext_vector_type(4)));
typedef unsigned int uint;
typedef unsigned short ushort;

__device__ __forceinline__ float b2f(ushort u) {
    return __uint_as_float(((uint)u) << 16);
}
__device__ __forceinline__ ushort f2b(float f) {
    uint u = __float_as_uint(f);
    u = (u + 0x7fffu + ((u >> 16) & 1u)) >> 16;   // RNE
    return (ushort)u;
}
// clamp that also kills NaN (fmaxf(NaN,a)=a on HIP)
__device__ __forceinline__ float sane(float x, float lim) {
    return fminf(fmaxf(x, -lim), lim);
}

// -------------------------------------------------- K_d: detect dtype + small converts
// mode 0 = float tensors are bf16; mode 1 = fp32.
__global__ __launch_bounds__(256) void detect_convert_small(
        const ushort* __restrict__ hraw,
        const void* __restrict__ a_src_raw, const void* __restrict__ a_dst_raw,
        const void* __restrict__ bias_raw,
        int* __restrict__ flag,
        ushort* __restrict__ asB, ushort* __restrict__ adB, ushort* __restrict__ biasB) {
    __shared__ int smode;
    int t = threadIdx.x;
    if (t < 64) {
        ushort u = hraw[2 * t];          // even position: bf16 value OR fp32 mantissa word
        int e = (u >> 7) & 0xFF;
        unsigned long long m = __ballot(e >= 90 && e <= 141);
        if (t == 0) {
            int mode = (__popcll(m) >= 40) ? 0 : 1;
            smode = mode;
            flag[0] = mode;
        }
    }
    __syncthreads();
    int mode = smode;
    const ushort* asU = (const ushort*)a_src_raw; const float* asF = (const float*)a_src_raw;
    const ushort* adU = (const ushort*)a_dst_raw; const float* adF = (const float*)a_dst_raw;
    const ushort* bU  = (const ushort*)bias_raw;  const float* bF  = (const float*)bias_raw;
    for (int i = t; i < NH * FOUT; i += 256) {
        asB[i] = mode ? f2b(asF[i]) : asU[i];
        adB[i] = mode ? f2b(adF[i]) : adU[i];
    }
    for (int i = t; i < FOUT; i += 256) biasB[i] = mode ? f2b(bF[i]) : bU[i];
}

// -------------------------------------------------- K_h: canonicalize h to bf16
__global__ __launch_bounds__(256) void convert_h(const void* __restrict__ hraw,
                                                 const int* __restrict__ flag,
                                                 ushort* __restrict__ hB) {
    int mode = flag[0];
    size_t base = ((size_t)blockIdx.x * 256 + threadIdx.x) * 8;
    alignas(16) ushort tmp[8];
    if (mode == 0) {
        *reinterpret_cast<uint4*>(tmp) = *reinterpret_cast<const uint4*>((const ushort*)hraw + base);
    } else {
        const float* hf = (const float*)hraw;
        float4 a = *reinterpret_cast<const float4*>(hf + base);
        float4 b = *reinterpret_cast<const float4*>(hf + base + 4);
        tmp[0]=f2b(a.x); tmp[1]=f2b(a.y); tmp[2]=f2b(a.z); tmp[3]=f2b(a.w);
        tmp[4]=f2b(b.x); tmp[5]=f2b(b.y); tmp[6]=f2b(b.z); tmp[7]=f2b(b.w);
    }
    *reinterpret_cast<uint4*>(hB + base) = *reinterpret_cast<uint4*>(tmp);
}

// -------------------------------------------------- K0: pack adj into transposed bitmask
__global__ __launch_bounds__(256) void pack_adj(const int* __restrict__ adj,
                                                uint* __restrict__ bitsT) {
    size_t idx = (size_t)blockIdx.x * 256 + threadIdx.x;
    int v = adj[idx];
    unsigned long long m = __ballot(v != 0);
    int lane = threadIdx.x & 63;
    uint i  = (uint)(idx >> 12);
    uint jw = ((uint)idx & 4095u) >> 5;
    if (lane == 0)       bitsT[jw * N + i] = (uint)m;
    else if (lane == 32) bitsT[jw * N + i] = (uint)(m >> 32);
}

// -------------------------------------------------- K0b: w -> wT[h][o][f] (bf16)
__global__ __launch_bounds__(256) void transpose_w(const void* __restrict__ wraw,
                                                   const int* __restrict__ flag,
                                                   ushort* __restrict__ wT) {
    __shared__ ushort tile[64][72];
    int mode = flag[0];
    int h = blockIdx.z, f0 = blockIdx.x * 64, o0 = blockIdx.y * 64;
    int t = threadIdx.x;
#pragma unroll
    for (int it = 0; it < 2; ++it) {
        int slot = it * 256 + t;
        int row = slot >> 3, c = slot & 7;
        size_t eoff = (size_t)h * (FIN * FOUT) + (size_t)(f0 + row) * FOUT + o0 + c * 8;
        alignas(16) ushort tmp[8];
        if (mode == 0) {
            *reinterpret_cast<uint4*>(tmp) = *reinterpret_cast<const uint4*>((const ushort*)wraw + eoff);
        } else {
            const float* wF = (const float*)wraw;
            float4 x = *reinterpret_cast<const float4*>(wF + eoff);
            float4 y = *reinterpret_cast<const float4*>(wF + eoff + 4);
            tmp[0]=f2b(x.x); tmp[1]=f2b(x.y); tmp[2]=f2b(x.z); tmp[3]=f2b(x.w);
            tmp[4]=f2b(y.x); tmp[5]=f2b(y.y); tmp[6]=f2b(y.z); tmp[7]=f2b(y.w);
        }
        *reinterpret_cast<uint4*>(&tile[row][c * 8]) = *reinterpret_cast<uint4*>(tmp);
    }
    __syncthreads();
#pragma unroll
    for (int it = 0; it < 2; ++it) {
        int slot = it * 256 + t;
        int orow = slot >> 3, c = slot & 7;
        alignas(16) ushort tmp[8];
#pragma unroll
        for (int k = 0; k < 8; ++k) tmp[k] = tile[c * 8 + k][orow];
        *reinterpret_cast<uint4*>(wT + (size_t)h * (FIN * FOUT) + (size_t)(o0 + orow) * FIN + f0 + c * 8) =
            *reinterpret_cast<uint4*>(tmp);
    }
}

// -------------------------------------------------- K1: hpT[h][o][i] = (h @ W_h)^T
#define LSTR 40
__global__ __launch_bounds__(256) void gemm_hp(const ushort* __restrict__ hB,
                                               const ushort* __restrict__ wT,
                                               ushort* __restrict__ hpT) {
    __shared__ ushort As[128 * LSTR];
    __shared__ ushort Bs[128 * LSTR];
    int tid = threadIdx.x;
    int head = blockIdx.x;
    int i0 = blockIdx.y * 128;
    const ushort* Ag = hB + (size_t)i0 * FIN;
    const ushort* Bg = wT + (size_t)head * (FIN * FOUT);
    int wave = tid >> 6, lane = tid & 63;
    int wm = wave >> 1, wn = wave & 1, quad = lane >> 4, l16 = lane & 15;

    f32x4 acc[4][4] = {};

    for (int k0 = 0; k0 < FIN; k0 += 32) {
        __syncthreads();
#pragma unroll
        for (int it = 0; it < 2; ++it) {
            int slot = it * 256 + tid;
            int row = slot >> 2, c = slot & 3;
            *reinterpret_cast<uint4*>(&As[row * LSTR + c * 8]) =
                *reinterpret_cast<const uint4*>(Ag + (size_t)row * FIN + k0 + c * 8);
            *reinterpret_cast<uint4*>(&Bs[row * LSTR + c * 8]) =
                *reinterpret_cast<const uint4*>(Bg + (size_t)row * FIN + k0 + c * 8);
        }
        __syncthreads();
        bf16x8 a[4], b[4];
#pragma unroll
        for (int m = 0; m < 4; ++m)
            a[m] = *reinterpret_cast<const bf16x8*>(&As[(wm * 64 + m * 16 + l16) * LSTR + quad * 8]);
#pragma unroll
        for (int n = 0; n < 4; ++n)
            b[n] = *reinterpret_cast<const bf16x8*>(&Bs[(wn * 64 + n * 16 + l16) * LSTR + quad * 8]);
#pragma unroll
        for (int m = 0; m < 4; ++m)
#pragma unroll
            for (int n = 0; n < 4; ++n)
                acc[m][n] = __builtin_amdgcn_mfma_f32_16x16x32_bf16(a[m], b[n], acc[m][n], 0, 0, 0);
    }
#pragma unroll
    for (int m = 0; m < 4; ++m) {
#pragma unroll
        for (int n = 0; n < 4; ++n) {
            int col = wn * 64 + n * 16 + l16;
            int rbase = i0 + wm * 64 + m * 16 + quad * 4;
            ushort4 pk;
            pk.x = f2b(sane(acc[m][n][0], 1000.f));
            pk.y = f2b(sane(acc[m][n][1], 1000.f));
            pk.z = f2b(sane(acc[m][n][2], 1000.f));
            pk.w = f2b(sane(acc[m][n][3], 1000.f));
            *reinterpret_cast<ushort4*>(hpT + (size_t)head * (FOUT * N) + (size_t)col * N + rbase) = pk;
        }
    }
}

// -------------------------------------------------- K2: s,d dots + exp tables
__global__ __launch_bounds__(256) void srcdst(const ushort* __restrict__ hpT,
                                              const ushort* __restrict__ asB,
                                              const ushort* __restrict__ adB,
                                              float* __restrict__ es1, float* __restrict__ es2,
                                              float* __restrict__ ed1, float* __restrict__ ed2) {
    int hh = blockIdx.y;
    int i = blockIdx.x * 256 + threadIdx.x;
    const ushort* base = hpT + (size_t)hh * (FOUT * N) + i;
    float s = 0.f, d = 0.f;
    for (int o = 0; o < FOUT; ++o) {
        float hv = b2f(base[(size_t)o * N]);
        s += hv * b2f(asB[hh * FOUT + o]);
        d += hv * b2f(adB[hh * FOUT + o]);
    }
    s = sane(s, 30.f);
    d = sane(d, 30.f);
    int idx = hh * N + i;
    es1[idx] = __expf(s);       es2[idx] = __expf(0.2f * s);
    ed1[idx] = __expf(d);       ed2[idx] = __expf(0.2f * d);
}

// -------------------------------------------------- K3: l row-sums
__global__ __launch_bounds__(256) void zero_lsum(float* __restrict__ lsum) {
    lsum[blockIdx.x * 256 + threadIdx.x] = 0.f;
}

__global__ __launch_bounds__(256) void rowsum(const float* __restrict__ es1, const float* __restrict__ es2,
                                              const float* __restrict__ ed1, const float* __restrict__ ed2,
                                              const uint* __restrict__ bitsT, float* __restrict__ lsum) {
    int hh = blockIdx.z;
    int i = blockIdx.x * 256 + threadIdx.x;
    int w0 = blockIdx.y * 32;
    float e1i = es1[hh * N + i], e2i = es2[hh * N + i];
    const float* p1 = ed1 + hh * N + w0 * 32;
    const float* p2 = ed2 + hh * N + w0 * 32;
    float acc = 0.f;
    for (int w = 0; w < 32; ++w) {
        uint word = bitsT[(size_t)(w0 + w) * N + i];
#pragma unroll
        for (int b = 0; b < 32; ++b) {
            float t1 = e1i * p1[w * 32 + b];
            float e = (t1 >= 1.0f) ? t1 : e2i * p2[w * 32 + b];
            acc += ((word >> b) & 1u) ? e : 0.f;
        }
    }
    atomicAdd(&lsum[hh * N + i], acc);
}

__global__ __launch_bounds__(256) void recip(const float* __restrict__ lsum,
                                             float* __restrict__ rinv) {
    int idx = blockIdx.x * 256 + threadIdx.x;
    float v = lsum[idx];
    rinv[idx] = (v > 1e-30f) ? 1.0f / v : 0.f;
}

// -------------------------------------------------- K4: output = P @ h' (+bias)
__global__ __launch_bounds__(256) void pv_kernel(const ushort* __restrict__ hpT,
                                                 const float* __restrict__ es1, const float* __restrict__ es2,
                                                 const float* __restrict__ ed1, const float* __restrict__ ed2,
                                                 const float* __restrict__ rinv,
                                                 const uint* __restrict__ bitsT,
                                                 const ushort* __restrict__ biasB,
                                                 const int* __restrict__ flag,
                                                 void* __restrict__ outraw) {
    __shared__ ushort Ps[128 * LSTR];
    __shared__ ushort Bs[128 * LSTR];
    __shared__ float ss1[128], ss2[128], rr[128];
    int mode = flag[0];
    int t = threadIdx.x;
    int i0 = blockIdx.x * 128;
    int hh = blockIdx.y;
    if (t < 128) {
        ss1[t] = es1[hh * N + i0 + t];
        ss2[t] = es2[hh * N + i0 + t];
        rr[t]  = rinv[hh * N + i0 + t];
    }
    int wave = t >> 6, lane = t & 63;
    int wm = wave >> 1, wn = wave & 1, quad = lane >> 4, l16 = lane & 15;
    int k2 = (t & 15) * 2;
    int tr = t >> 4;
    const ushort* Bg = hpT + (size_t)hh * (FOUT * N);
    f32x4 acc[4][4] = {};

    for (int k0 = 0; k0 < N; k0 += 32) {
        __syncthreads();
#pragma unroll
        for (int st = 0; st < 2; ++st) {
            int slot = st * 256 + t;
            int row = slot >> 2, c = slot & 3;
            *reinterpret_cast<uint4*>(&Bs[row * LSTR + c * 8]) =
                *reinterpret_cast<const uint4*>(Bg + (size_t)row * N + k0 + c * 8);
        }
        float2 d1 = *reinterpret_cast<const float2*>(ed1 + hh * N + k0 + k2);
        float2 d2 = *reinterpret_cast<const float2*>(ed2 + hh * N + k0 + k2);
        int wix = (k0 >> 5) * N + i0;
#pragma unroll
        for (int e = 0; e < 8; ++e) {
            int irow = e * 16 + tr;
            uint word = bitsT[wix + irow];
            float s1 = ss1[irow], s2 = ss2[irow], r = rr[irow];
            float t1a = s1 * d1.x;
            float ea = (t1a >= 1.0f) ? t1a : s2 * d2.x;
            ea = ((word >> k2) & 1u) ? ea * r : 0.f;
            float t1b = s1 * d1.y;
            float eb = (t1b >= 1.0f) ? t1b : s2 * d2.y;
            eb = ((word >> (k2 + 1)) & 1u) ? eb * r : 0.f;
            uint packed = (uint)f2b(ea) | ((uint)f2b(eb) << 16);
            *reinterpret_cast<uint*>(&Ps[irow * LSTR + k2]) = packed;
        }
        __syncthreads();
        bf16x8 a[4], b[4];
#pragma unroll
        for (int m = 0; m < 4; ++m)
            a[m] = *reinterpret_cast<const bf16x8*>(&Ps[(wm * 64 + m * 16 + l16) * LSTR + quad * 8]);
#pragma unroll
        for (int n = 0; n < 4; ++n)
            b[n] = *reinterpret_cast<const bf16x8*>(&Bs[(wn * 64 + n * 16 + l16) * LSTR + quad * 8]);
#pragma unroll
        for (int m = 0; m < 4; ++m)
#pragma unroll
            for (int n = 0; n < 4; ++n)
                acc[m][n] = __builtin_amdgcn_mfma_f32_16x16x32_bf16(a[m], b[n], acc[m][n], 0, 0, 0);
    }
    ushort* outU = (ushort*)outraw;
    float*  outF = (float*)outraw;
#pragma unroll
    for (int m = 0; m < 4; ++m) {
#pragma unroll
        for (int n = 0; n < 4; ++n) {
            int col = wn * 64 + n * 16 + l16;
            float bv = b2f(biasB[col]);
#pragma unroll
            for (int r = 0; r < 4; ++r) {
                int row = wm * 64 + m * 16 + quad * 4 + r;
                size_t oidx = (size_t)(i0 + row) * (NH * FOUT) + hh * FOUT + col;
                float val = sane(acc[m][n][r] + bv, 60000.f);
                if (mode == 0) outU[oidx] = f2b(val);
                else           outF[oidx] = val;
            }
        }
    }
}

// -------------------------------------------------- K5: weight = sum_h attn
__global__ __launch_bounds__(256) void weight_kernel(const float* __restrict__ es1, const float* __restrict__ es2,
                                                     const float* __restrict__ ed1, const float* __restrict__ ed2,
                                                     const float* __restrict__ rinv,
                                                     const uint* __restrict__ bitsT,
                                                     const int* __restrict__ flag,
                                                     void* __restrict__ outraw) {
    int mode = flag[0];
    ushort* woutU = (ushort*)outraw + (size_t)N * (NH * FOUT);
    float*  woutF = (float*)outraw  + (size_t)N * (NH * FOUT);
    int t = threadIdx.x;
    int i0 = blockIdx.x * 16;
    int j0 = blockIdx.y * 1024;
    for (int ji = 0; ji < 4; ++ji) {
        int j = j0 + ji * 256 + t;
        float d1[NH], d2[NH];
#pragma unroll
        for (int hh = 0; hh < NH; ++hh) {
            d1[hh] = ed1[hh * N + j];
            d2[hh] = ed2[hh * N + j];
        }
        int wrow = j >> 5;
        int jb = j & 31;
        for (int i = i0; i < i0 + 16; ++i) {
            uint word = bitsT[(size_t)wrow * N + i];
            float sum = 0.f;
#pragma unroll
            for (int hh = 0; hh < NH; ++hh) {
                float s1 = es1[hh * N + i];
                float s2 = es2[hh * N + i];
                float r  = rinv[hh * N + i];
                float t1 = s1 * d1[hh];
                float e = (t1 >= 1.0f) ? t1 : s2 * d2[hh];
                sum += e * r;
            }
            sum = ((word >> jb) & 1u) ? sane(sum, 60000.f) : 0.f;
            size_t oidx = (size_t)i * N + j;
            if (mode == 0) woutU[oidx] = f2b(sum);
            else           woutF[oidx] = sum;
        }
    }
}

// -------------------------------------------------- launch
extern "C" void kernel_launch(void* const* d_in, const int* in_sizes, int n_in,
                              void* d_out, int out_size, void* d_ws, size_t ws_size,
                              hipStream_t stream) {
    (void)in_sizes; (void)n_in; (void)out_size; (void)ws_size;
    const void* hraw  = d_in[0];                 // [4096][1024]  bf16 or fp32
    const int*  adj   = (const int*)d_in[1];     // [4096][4096]  int32
    const void* wraw  = d_in[2];                 // [8][1024][128]
    const void* braw  = d_in[3];                 // [128]
    const void* asraw = d_in[4];                 // [8][128]
    const void* adraw = d_in[5];                 // [8][128]

    // small scratch in ws (<3 MiB)
    char* ws = (char*)d_ws;
    int*    flag  = (int*)(ws);
    ushort* biasB = (ushort*)(ws + 256);
    ushort* asB   = (ushort*)(ws + 512);
    ushort* adB   = (ushort*)(ws + 2560);
    float*  es1   = (float*)(ws + 65536);
    float*  es2   = (float*)(ws + 196608);
    float*  ed1   = (float*)(ws + 327680);
    float*  ed2   = (float*)(ws + 458752);
    float*  rinv  = (float*)(ws + 589824);
    float*  lsum  = (float*)(ws + 720896);
    uint*   bitsT = (uint*)(ws + 851968);        // 2 MiB

    // big scratch inside d_out's weight region (weight_kernel writes it LAST).
    // byte offsets >= 16 MiB are beyond the `output` tensor in both dtype modes.
    char* ob = (char*)d_out;
    ushort* hB  = (ushort*)(ob + 16777216);      // 8 MiB canonical bf16 h
    ushort* hpT = (ushort*)(ob + 25165824);      // 8 MiB [8][128][4096]
    ushort* wT  = (ushort*)(ob + 33554432);      // 2 MiB [8][128][1024]

    detect_convert_small<<<1, 256, 0, stream>>>((const ushort*)hraw, asraw, adraw, braw,
                                                flag, asB, adB, biasB);
    convert_h<<<2048, 256, 0, stream>>>(hraw, flag, hB);
    pack_adj<<<(N * (size_t)N) / 256, 256, 0, stream>>>(adj, bitsT);
    transpose_w<<<dim3(16, 2, 8), 256, 0, stream>>>(wraw, flag, wT);
    gemm_hp<<<dim3(8, 32), 256, 0, stream>>>(hB, wT, hpT);
    srcdst<<<dim3(16, 8), 256, 0, stream>>>(hpT, asB, adB, es1, es2, ed1, ed2);
    zero_lsum<<<128, 256, 0, stream>>>(lsum);
    rowsum<<<dim3(16, 4, 8), 256, 0, stream>>>(es1, es2, ed1, ed2, bitsT, lsum);
    recip<<<128, 256, 0, stream>>>(lsum, rinv);
    pv_kernel<<<dim3(32, 8), 256, 0, stream>>>(hpT, es1, es2, ed1, ed2, rinv, bitsT,
                                               biasB, flag, d_out);
    weight_kernel<<<dim3(256, 4), 256, 0, stream>>>(es1, es2, ed1, ed2, rinv, bitsT,
                                                    flag, d_out);
}